// Round 10
// baseline (866.896 us; speedup 1.0000x reference)
//
#include <hip/hip_runtime.h>

#define NN   50000
#define EE   800000
#define INC  128
#define OUTC 256
#define HALF 128
#define NREL 6
#define NCELL (NN * NREL)   // 300000
#define NPAD 50048          // 391*128

typedef __attribute__((ext_vector_type(4))) short s16x4;
typedef __attribute__((ext_vector_type(8))) short bf16x8;
typedef __attribute__((ext_vector_type(4))) float f32x4;

__device__ __forceinline__ float b2f(short b) {
    unsigned u = ((unsigned)(unsigned short)b) << 16;
    return __uint_as_float(u);
}
__device__ __forceinline__ short f2b(float f) {
    unsigned u = __float_as_uint(f);
    unsigned r = (u + 0x7fffu + ((u >> 16) & 1u)) >> 16;   // RNE
    return (short)r;
}

__device__ __forceinline__ void gload16(const void* g, void* l) {
    __builtin_amdgcn_global_load_lds(
        (const __attribute__((address_space(1))) void*)g,
        (__attribute__((address_space(3))) void*)l, 16, 0, 0);
}

// streaming (no-allocate) ops for write-once/read-once buffers (H, out).
// NOTE: must use clang ext_vector types (s16x4/bf16x8/f32x4) — HIP's float4
// is a class and __builtin_nontemporal_* rejects it (R9 compile failure).
template<typename T>
__device__ __forceinline__ void nts(T v, T* p) { __builtin_nontemporal_store(v, p); }
template<typename T>
__device__ __forceinline__ T ntl(const T* p) { return __builtin_nontemporal_load(p); }

// ---------------- CSR build ----------------
__global__ __launch_bounds__(256) void count_k(const int* __restrict__ dst,
                                               const int* __restrict__ et,
                                               int* __restrict__ cnt) {
    int e = blockIdx.x * 256 + threadIdx.x;
    if (e < EE) atomicAdd(&cnt[dst[e] * NREL + et[e]], 1);
}

__global__ __launch_bounds__(256) void scanA_k(const int* __restrict__ cnt,
                                               int* __restrict__ off,
                                               int* __restrict__ bsum, int n) {
    __shared__ int sh[256];
    int t = threadIdx.x;
    int base = blockIdx.x * 512 + t * 2;
    int v0 = (base < n) ? cnt[base] : 0;
    int v1 = (base + 1 < n) ? cnt[base + 1] : 0;
    int s = v0 + v1;
    sh[t] = s; __syncthreads();
    for (int o = 1; o < 256; o <<= 1) {
        int u = (t >= o) ? sh[t - o] : 0;
        __syncthreads();
        sh[t] += u;
        __syncthreads();
    }
    int excl = sh[t] - s;
    if (base < n)     off[base]     = excl;
    if (base + 1 < n) off[base + 1] = excl + v0;
    if (t == 255) bsum[blockIdx.x] = sh[255];
}

__global__ __launch_bounds__(1024) void scanB_k(int* __restrict__ bsum, int nb) {
    __shared__ int sh[1024];
    int t = threadIdx.x;
    int s = (t < nb) ? bsum[t] : 0;
    sh[t] = s; __syncthreads();
    for (int o = 1; o < 1024; o <<= 1) {
        int u = (t >= o) ? sh[t - o] : 0;
        __syncthreads();
        sh[t] += u;
        __syncthreads();
    }
    if (t < nb) bsum[t] = sh[t] - s;
}

__global__ __launch_bounds__(256) void scanC_k(int* __restrict__ off,
                                               const int* __restrict__ bsum, int n) {
    int i = blockIdx.x * 256 + threadIdx.x;
    if (i < n) off[i] += bsum[i >> 9];
    if (i == 0) off[n] = EE;
}

__global__ __launch_bounds__(256) void copyint_k(const int* __restrict__ a,
                                                 int* __restrict__ b, int n) {
    int i = blockIdx.x * 256 + threadIdx.x;
    if (i < n) b[i] = a[i];
}

__global__ __launch_bounds__(256) void fill_k(const int* __restrict__ src,
                                              const int* __restrict__ dst,
                                              const int* __restrict__ et,
                                              int* __restrict__ cur,
                                              int* __restrict__ es) {
    int e = blockIdx.x * 256 + threadIdx.x;
    if (e < EE) {
        int key = dst[e] * NREL + et[e];
        int p = atomicAdd(&cur[key], 1);
        es[p] = src[e];
    }
}

// ---------------- casts ----------------
__global__ __launch_bounds__(256) void cast_x_k(const float* __restrict__ x,
                                                short* __restrict__ xb, int n4) {
    int i = blockIdx.x * 256 + threadIdx.x;
    if (i < n4) {
        float4 v = ((const float4*)x)[i];
        s16x4 o;
        o[0] = f2b(v.x); o[1] = f2b(v.y); o[2] = f2b(v.z); o[3] = f2b(v.w);
        ((s16x4*)xb)[i] = o;
    }
}

// BT[Ncols][K] = [root | W_0 .. W_5]^T (bf16).  root: [K][D], W: [NREL][K][D].
// Encoder matrices: W==null, Ncols==D.
__global__ __launch_bounds__(256) void wtcat2_k(const float* __restrict__ root,
                                                const float* __restrict__ W,
                                                int K, int D, int Ncols,
                                                short* __restrict__ BT) {
    int i = blockIdx.x * 256 + threadIdx.x;
    if (i >= Ncols * K) return;
    int n = i / K, k = i - n * K;
    float v;
    if (n < D) {
        v = root[(size_t)k * D + n];
    } else {
        int nn = n - D;
        int r = nn / D, c = nn - r * D;
        v = W[((size_t)r * K + k) * D + c];
    }
    BT[(size_t)n * K + k] = f2b(v);
}

// ---------------- dual-problem bf16 MFMA GEMM ----------------
// blockIdx.y < nby1 -> problem 1, else problem 2.  Both share M and K.
// Single-buffer 2-barrier K-loop; LDS-slab epilogue with NON-TEMPORAL
// (no-allocate) stores: C buffers (H, e, out) are write-once/read-once, and
// R4/R8 proved the TCC write-allocate RFO (~154 MB FETCH on H) survives
// full-line-coverage stores -> nt policy is the remaining knob.
#define ACH(R, q) ((((R) << 2) | ((q) ^ ((R) & 3) ^ (((R) >> 2) & 1))) * 8)

__global__ __launch_bounds__(256) void gemm2_k(
    const short* __restrict__ A1, const short* __restrict__ B1,
    const float* __restrict__ bias1, int relu1,
    short* __restrict__ Cb1, int ldcb1, float* __restrict__ Cf1, int ldcf1,
    const short* __restrict__ A2, const short* __restrict__ B2,
    const float* __restrict__ bias2, int relu2,
    short* __restrict__ Cb2, int ldcb2, float* __restrict__ Cf2, int ldcf2,
    int M, int K, int nby1) {
    __shared__ __align__(16) char smem[16384];
    short* As = (short*)smem;                // [128*32] bf16
    short* Bs = As + 128 * 32;               // [128*32] bf16
    const int tid = threadIdx.x;
    const int wave = tid >> 6, lane = tid & 63;
    const int wm = (wave & 1) * 64, wn = (wave >> 1) * 64;
    const int l16 = lane & 15, quad = lane >> 4;
    const int bm = blockIdx.x * 128;

    const short* A; const short* BT; const float* bias;
    int relu; short* Cb; int ldcb; float* Cf; int ldcf; int bn;
    if ((int)blockIdx.y < nby1) {
        A = A1; BT = B1; bias = bias1; relu = relu1;
        Cb = Cb1; ldcb = ldcb1; Cf = Cf1; ldcf = ldcf1;
        bn = blockIdx.y * 128;
    } else {
        A = A2; BT = B2; bias = bias2; relu = relu2;
        Cb = Cb2; ldcb = ldcb2; Cf = Cf2; ldcf = ldcf2;
        bn = (blockIdx.y - nby1) * 128;
    }

    // staging slots (linear DMA dest == tid order), pre-swizzled source coords
    const int s0 = tid, s1 = tid + 256;
    const int r0 = s0 >> 2, c0 = (s0 & 3) ^ (r0 & 3) ^ ((r0 >> 2) & 1);
    const int r1 = s1 >> 2, c1 = (s1 & 3) ^ (r1 & 3) ^ ((r1 >> 2) & 1);

    f32x4 acc[4][4];
    #pragma unroll
    for (int i = 0; i < 4; ++i)
        #pragma unroll
        for (int j = 0; j < 4; ++j)
            acc[i][j] = (f32x4)0.f;

    for (int k0 = 0; k0 < K; k0 += 32) {
        gload16(A + (size_t)(bm + r0) * K + k0 + c0 * 8, As + s0 * 8);
        gload16(A + (size_t)(bm + r1) * K + k0 + c1 * 8, As + s1 * 8);
        gload16(BT + (size_t)(bn + r0) * K + k0 + c0 * 8, Bs + s0 * 8);
        gload16(BT + (size_t)(bn + r1) * K + k0 + c1 * 8, Bs + s1 * 8);
        __syncthreads();
        bf16x8 af[4], bf[4];
        #pragma unroll
        for (int mt = 0; mt < 4; ++mt)
            af[mt] = *(const bf16x8*)&As[ACH(wm + mt * 16 + l16, quad)];
        #pragma unroll
        for (int nt = 0; nt < 4; ++nt)
            bf[nt] = *(const bf16x8*)&Bs[ACH(wn + nt * 16 + l16, quad)];
        #pragma unroll
        for (int mt = 0; mt < 4; ++mt)
            #pragma unroll
            for (int nt = 0; nt < 4; ++nt)
                acc[mt][nt] = __builtin_amdgcn_mfma_f32_16x16x32_bf16(
                    af[mt], bf[nt], acc[mt][nt], 0, 0, 0);
        __syncthreads();
    }

    float bv[4];
    #pragma unroll
    for (int nt = 0; nt < 4; ++nt)
        bv[nt] = bias ? bias[bn + wn + nt * 16 + l16] : 0.f;

    // slab row: sr = (wave&1)*16 + quad*4 + r  <->  grow = bm + (sr>>4)*64 + mt*16 + (sr&15)
    if (Cb) {
        short* Es = (short*)smem;            // [32][128] bf16 slab
        #pragma unroll
        for (int mt = 0; mt < 4; ++mt) {
            __syncthreads();
            int srb = (wave & 1) * 16 + quad * 4;
            #pragma unroll
            for (int nt = 0; nt < 4; ++nt) {
                int sc = wn + nt * 16 + l16;
                #pragma unroll
                for (int r = 0; r < 4; ++r) {
                    float v = acc[mt][nt][r] + bv[nt];
                    if (relu) v = fmaxf(v, 0.f);
                    Es[(srb + r) * 128 + sc] = f2b(v);
                }
            }
            __syncthreads();
            #pragma unroll
            for (int h = 0; h < 2; ++h) {
                int c = tid + h * 256;       // chunk 0..511: 32 rows x 16 chunks
                int rr = c >> 4, cc = c & 15;
                int grow = bm + (rr >> 4) * 64 + mt * 16 + (rr & 15);
                if (grow < M)
                    nts(*(const bf16x8*)&Es[rr * 128 + cc * 8],
                        (bf16x8*)(Cb + (size_t)grow * ldcb + bn + cc * 8));
            }
        }
    } else {
        float* Ef = (float*)smem;            // [32][128] f32 slab (16 KB)
        #pragma unroll
        for (int mt = 0; mt < 4; ++mt) {
            __syncthreads();
            int srb = (wave & 1) * 16 + quad * 4;
            #pragma unroll
            for (int nt = 0; nt < 4; ++nt) {
                int sc = wn + nt * 16 + l16;
                #pragma unroll
                for (int r = 0; r < 4; ++r) {
                    float v = acc[mt][nt][r] + bv[nt];
                    if (relu) v = fmaxf(v, 0.f);
                    Ef[(srb + r) * 128 + sc] = v;
                }
            }
            __syncthreads();
            #pragma unroll
            for (int h = 0; h < 4; ++h) {
                int c = tid + h * 256;       // chunk 0..1023: 32 rows x 32 chunks
                int rr = c >> 5, cc = c & 31;
                int grow = bm + (rr >> 4) * 64 + mt * 16 + (rr & 15);
                if (grow < M)
                    nts(*(const f32x4*)&Ef[rr * 128 + cc * 4],
                        (f32x4*)(Cf + (size_t)grow * ldcf + bn + cc * 4));
            }
        }
    }
}

// ---------------- post-GEMM gather-aggregate ----------------
// out[i] = (accin? accin[i]:0) + (self0? H[i, 0:D]:0)
//        + sum_{r in [rfirst,rlast)} mean_{j in cell(i,r)} H[j, (colbase+r)*D : +D]
//        (+bias, +relu).  H reads are non-temporal (read-once stream).
// H layout [root | W_0..W_5] -> full-H callers pass colbase=1.
template<int D>
__global__ __launch_bounds__(256) void gagg_k(
    const short* __restrict__ H, int ldh,
    int rfirst, int rlast, int colbase, int self0,
    const int* __restrict__ off, const int* __restrict__ es,
    const float* __restrict__ accin,
    const float* __restrict__ bias, int relu,
    short* __restrict__ Ob, float* __restrict__ Of, int ldo) {
    constexpr int LPN = D / 4;          // lanes per node (64 or 32)
    constexpr int NPB = 256 / LPN;      // nodes per block (4 or 8)
    int sub = threadIdx.x / LPN, lane = threadIdx.x % LPN;
    int node = blockIdx.x * NPB + sub;
    if (node >= NN) return;
    int c0 = lane * 4;

    float a0, a1, a2, a3;
    if (accin) {
        float4 t = *(const float4*)(accin + (size_t)node * D + c0);
        a0 = t.x; a1 = t.y; a2 = t.z; a3 = t.w;
    } else {
        a0 = a1 = a2 = a3 = 0.f;
    }
    if (self0) {
        s16x4 v = ntl((const s16x4*)(H + (size_t)node * ldh + c0));
        a0 += b2f(v[0]); a1 += b2f(v[1]); a2 += b2f(v[2]); a3 += b2f(v[3]);
    }
    int cell0 = node * NREL;
    for (int r = rfirst; r < rlast; ++r) {
        int beg = off[cell0 + r], end = off[cell0 + r + 1];
        if (end == beg) continue;
        int colo = (colbase + r) * D + c0;
        float s0 = 0.f, s1 = 0.f, s2 = 0.f, s3 = 0.f;
        int j = beg;
        for (; j + 3 < end; j += 4) {
            s16x4 v0 = ntl((const s16x4*)(H + (size_t)es[j] * ldh + colo));
            s16x4 v1 = ntl((const s16x4*)(H + (size_t)es[j + 1] * ldh + colo));
            s16x4 v2 = ntl((const s16x4*)(H + (size_t)es[j + 2] * ldh + colo));
            s16x4 v3 = ntl((const s16x4*)(H + (size_t)es[j + 3] * ldh + colo));
            s0 += b2f(v0[0]) + b2f(v1[0]) + b2f(v2[0]) + b2f(v3[0]);
            s1 += b2f(v0[1]) + b2f(v1[1]) + b2f(v2[1]) + b2f(v3[1]);
            s2 += b2f(v0[2]) + b2f(v1[2]) + b2f(v2[2]) + b2f(v3[2]);
            s3 += b2f(v0[3]) + b2f(v1[3]) + b2f(v2[3]) + b2f(v3[3]);
        }
        for (; j < end; ++j) {
            s16x4 v = ntl((const s16x4*)(H + (size_t)es[j] * ldh + colo));
            s0 += b2f(v[0]); s1 += b2f(v[1]); s2 += b2f(v[2]); s3 += b2f(v[3]);
        }
        float inv = 1.f / (float)(end - beg);
        a0 += s0 * inv; a1 += s1 * inv; a2 += s2 * inv; a3 += s3 * inv;
    }
    if (bias) {
        float4 bv = *(const float4*)(bias + c0);
        a0 += bv.x; a1 += bv.y; a2 += bv.z; a3 += bv.w;
    }
    if (relu) {
        a0 = fmaxf(a0, 0.f); a1 = fmaxf(a1, 0.f);
        a2 = fmaxf(a2, 0.f); a3 = fmaxf(a3, 0.f);
    }
    if (Ob) {
        s16x4 o;
        o[0] = f2b(a0); o[1] = f2b(a1); o[2] = f2b(a2); o[3] = f2b(a3);
        *(s16x4*)(Ob + (size_t)node * ldo + c0) = o;   // g1/g2: reused -> cached
    } else {
        f32x4 o;
        o[0] = a0; o[1] = a1; o[2] = a2; o[3] = a3;
        nts(o, (f32x4*)(Of + (size_t)node * ldo + c0)); // out: final -> nt
    }
}

// ---------------- host ----------------
extern "C" void kernel_launch(void* const* d_in, const int* in_sizes, int n_in,
                              void* d_out, int out_size, void* d_ws, size_t ws_size,
                              hipStream_t stream) {
    const float* x      = (const float*)d_in[0];
    const int*   ei     = (const int*)d_in[1];
    const int*   srcv   = ei;
    const int*   dstv   = ei + EE;
    const int*   et     = (const int*)d_in[2];
    const float* enc_w0 = (const float*)d_in[3];
    const float* enc_b0 = (const float*)d_in[4];
    const float* enc_w1 = (const float*)d_in[5];
    const float* enc_b1 = (const float*)d_in[6];
    const float* enc_w2 = (const float*)d_in[7];
    const float* enc_b2 = (const float*)d_in[8];
    const float* W1     = (const float*)d_in[9];
    const float* root1  = (const float*)d_in[10];
    const float* b1     = (const float*)d_in[11];
    const float* W2     = (const float*)d_in[12];
    const float* root2  = (const float*)d_in[13];
    const float* b2     = (const float*)d_in[14];
    const float* W3     = (const float*)d_in[15];
    const float* root3  = (const float*)d_in[16];
    const float* b3     = (const float*)d_in[17];
    float* out = (float*)d_out;

    char* p = (char*)d_ws;
    auto alloc = [&](size_t bytes) -> char* {
        char* r = p; p += (bytes + 255) & ~(size_t)255; return r;
    };
    short* xb  = (short*)alloc((size_t)NPAD * INC * 2);
    short* g1  = (short*)alloc((size_t)NPAD * OUTC * 2);
    short* g2  = (short*)alloc((size_t)NPAD * OUTC * 2);
    short* BT1 = (short*)alloc((size_t)1792 * INC * 2);    // [root1|W1_0..5]^T
    short* BT2 = (short*)alloc((size_t)1792 * OUTC * 2);   // [root2|W2_0..5]^T
    short* BT3 = (short*)alloc((size_t)896 * OUTC * 2);    // [root3|W3_0..5]^T
    short* ET0 = (short*)alloc((size_t)OUTC * INC * 2);
    short* ET1 = (short*)alloc((size_t)OUTC * OUTC * 2);
    short* ET2 = (short*)alloc((size_t)HALF * OUTC * 2);
    int* CNT  = (int*)alloc((size_t)NCELL * 4);
    int* OFF  = (int*)alloc((size_t)(NCELL + 1) * 4);
    int* CUR  = (int*)alloc((size_t)NCELL * 4);
    int* ES   = (int*)alloc((size_t)EE * 4);
    int* BSUM = (int*)alloc(1024 * 4);
    size_t fixed = (size_t)(p - (char*)d_ws);

    const size_t Hfull = (size_t)NPAD * 1792 * 2;
    const size_t Esz   = (size_t)NPAD * OUTC * 2;
    // Tier A: full H + e1/e2 (batched conv+enc GEMMs).
    // Tier B: full H, sequential encoder.  Tier C: relation-split two-pass.
    bool tierA = fixed + Hfull + 2 * Esz + 1024 <= ws_size;
    bool fullH = tierA || (fixed + Hfull + 1024 <= ws_size);
    short* H = (short*)alloc(fullH ? Hfull : (size_t)NPAD * 1024 * 2);
    short* e1 = nullptr; short* e2 = nullptr; float* ACC = nullptr;
    if (tierA) { e1 = (short*)alloc(Esz); e2 = (short*)alloc(Esz); }
    if (!fullH) ACC = (float*)alloc((size_t)NPAD * OUTC * 4);

    // ---- CSR build (once; edge structure shared by all 3 layers)
    hipMemsetAsync(CNT, 0, (size_t)NCELL * 4, stream);
    count_k<<<EE / 256, 256, 0, stream>>>(dstv, et, CNT);
    int nbA = (NCELL + 511) / 512;
    scanA_k<<<nbA, 256, 0, stream>>>(CNT, OFF, BSUM, NCELL);
    scanB_k<<<1, 1024, 0, stream>>>(BSUM, nbA);
    scanC_k<<<(NCELL + 255) / 256, 256, 0, stream>>>(OFF, BSUM, NCELL);
    copyint_k<<<(NCELL + 255) / 256, 256, 0, stream>>>(OFF, CUR, NCELL);
    fill_k<<<EE / 256, 256, 0, stream>>>(srcv, dstv, et, CUR, ES);

    // ---- weight transposes + input cast
    cast_x_k<<<(NN * INC / 4 + 255) / 256, 256, 0, stream>>>(x, xb, NN * INC / 4);
    auto wt = [&](const float* root, const float* W, int K, int D, int Ncols, short* BT) {
        wtcat2_k<<<(Ncols * K + 255) / 256, 256, 0, stream>>>(root, W, K, D, Ncols, BT);
    };
    wt(root1, W1, INC, OUTC, 1792, BT1);
    wt(root2, W2, OUTC, OUTC, 1792, BT2);
    wt(root3, W3, OUTC, HALF, 896, BT3);
    wt(enc_w0, nullptr, INC, OUTC, OUTC, ET0);
    wt(enc_w1, nullptr, OUTC, OUTC, OUTC, ET1);
    wt(enc_w2, nullptr, OUTC, HALF, HALF, ET2);

    // single-problem GEMM (duplicated descriptor)
    auto gemm1 = [&](const short* A, const short* BT, int M, int K, int Ncols,
                     const float* bias, int relu, short* Cb, int ldcb, float* Cf, int ldcf) {
        dim3 grid((M + 127) / 128, Ncols / 128);
        gemm2_k<<<grid, 256, 0, stream>>>(A, BT, bias, relu, Cb, ldcb, Cf, ldcf,
                                          A, BT, bias, relu, Cb, ldcb, Cf, ldcf,
                                          M, K, grid.y);
    };

    if (tierA) {
        // ---- batch 1: [conv1-H (N=1792) | enc1 (N=256)], K=128, A=xb both
        gemm2_k<<<dim3(391, 16), 256, 0, stream>>>(
            xb, BT1, nullptr, 0, H, 1792, nullptr, 0,
            xb, ET0, enc_b0, 1, e1, OUTC, nullptr, 0,
            NN, INC, 14);
        gagg_k<256><<<12500, 256, 0, stream>>>(H, 1792, 0, NREL, 1, 1,
            OFF, ES, nullptr, b1, 1, g1, nullptr, OUTC);
        // ---- batch 2: [conv2-H (N=1792, A=g1) | enc2 (N=256, A=e1)], K=256
        gemm2_k<<<dim3(391, 16), 256, 0, stream>>>(
            g1, BT2, nullptr, 0, H, 1792, nullptr, 0,
            e1, ET1, enc_b1, 1, e2, OUTC, nullptr, 0,
            NN, OUTC, 14);
        gagg_k<256><<<12500, 256, 0, stream>>>(H, 1792, 0, NREL, 1, 1,
            OFF, ES, nullptr, b2, 1, g2, nullptr, OUTC);
        // ---- batch 3: [conv3-H (N=896, A=g2) | enc3 (N=128, A=e2 -> out f32)], K=256
        gemm2_k<<<dim3(391, 8), 256, 0, stream>>>(
            g2, BT3, nullptr, 0, H, 896, nullptr, 0,
            e2, ET2, enc_b2, 0, nullptr, 0, out, OUTC,
            NN, OUTC, 7);
        gagg_k<128><<<6250, 256, 0, stream>>>(H, 896, 0, NREL, 1, 1,
            OFF, ES, nullptr, b3, 0, nullptr, out + HALF, OUTC);
        return;
    }

    // ---- fallback: sequential encoder, then conv layers
    gemm1(xb, ET0, NN, INC, OUTC, enc_b0, 1, g1, OUTC, nullptr, 0);
    gemm1(g1, ET1, NN, OUTC, OUTC, enc_b1, 1, g2, OUTC, nullptr, 0);
    gemm1(g2, ET2, NN, OUTC, HALF, enc_b2, 0, nullptr, 0, out, OUTC);

    auto conv = [&](const short* A, int K, int D, const short* BT,
                    const float* bias, int relu, short* Ob, float* Of) {
        int NPB = 256 / (D / 4);
        int gg = (NN + NPB - 1) / NPB;
        if (fullH) {
            gemm1(A, BT, NN, K, 7 * D, nullptr, 0, H, 7 * D, nullptr, 0);
            if (D == 256)
                gagg_k<256><<<gg, 256, 0, stream>>>(H, 7 * D, 0, NREL, 1, 1,
                    OFF, ES, nullptr, bias, relu, Ob, Of, OUTC);
            else
                gagg_k<128><<<gg, 256, 0, stream>>>(H, 7 * D, 0, NREL, 1, 1,
                    OFF, ES, nullptr, bias, relu, Ob, Of, OUTC);
        } else {
            gemm1(A, BT, NN, K, 4 * D, nullptr, 0, H, 4 * D, nullptr, 0);
            if (D == 256)
                gagg_k<256><<<gg, 256, 0, stream>>>(H, 4 * D, 0, 3, 1, 1,
                    OFF, ES, nullptr, nullptr, 0, nullptr, ACC, D);
            else
                gagg_k<128><<<gg, 256, 0, stream>>>(H, 4 * D, 0, 3, 1, 1,
                    OFF, ES, nullptr, nullptr, 0, nullptr, ACC, D);
            gemm1(A, BT + (size_t)4 * D * (size_t)K, NN, K, 3 * D, nullptr, 0, H, 3 * D, nullptr, 0);
            if (D == 256)
                gagg_k<256><<<gg, 256, 0, stream>>>(H, 3 * D, 3, NREL, -3, 0,
                    OFF, ES, ACC, bias, relu, Ob, Of, OUTC);
            else
                gagg_k<128><<<gg, 256, 0, stream>>>(H, 3 * D, 3, NREL, -3, 0,
                    OFF, ES, ACC, bias, relu, Ob, Of, OUTC);
        }
    };

    conv(xb, INC,  OUTC, BT1, b1, 1, g1, nullptr);        // conv1: K=128, N=1792
    conv(g1, OUTC, OUTC, BT2, b2, 1, g2, nullptr);        // conv2: K=256, N=1792
    conv(g2, OUTC, HALF, BT3, b3, 0, nullptr, out + HALF);// conv3: K=256, N=896
}

// Round 11
// 736.193 us; speedup vs baseline: 1.1775x; 1.1775x over previous
//
#include <hip/hip_runtime.h>

#define NN   50000
#define EE   800000
#define INC  128
#define OUTC 256
#define HALF 128
#define NREL 6
#define NCELL (NN * NREL)   // 300000
#define NPAD 50048          // 391*128

typedef __attribute__((ext_vector_type(4))) short s16x4;
typedef __attribute__((ext_vector_type(8))) short bf16x8;
typedef __attribute__((ext_vector_type(4))) float f32x4;

__device__ __forceinline__ float b2f(short b) {
    unsigned u = ((unsigned)(unsigned short)b) << 16;
    return __uint_as_float(u);
}
__device__ __forceinline__ short f2b(float f) {
    unsigned u = __float_as_uint(f);
    unsigned r = (u + 0x7fffu + ((u >> 16) & 1u)) >> 16;   // RNE
    return (short)r;
}

__device__ __forceinline__ void gload16(const void* g, void* l) {
    __builtin_amdgcn_global_load_lds(
        (const __attribute__((address_space(1))) void*)g,
        (__attribute__((address_space(3))) void*)l, 16, 0, 0);
}

// ---------------- CSR build ----------------
__global__ __launch_bounds__(256) void count_k(const int* __restrict__ dst,
                                               const int* __restrict__ et,
                                               int* __restrict__ cnt) {
    int e = blockIdx.x * 256 + threadIdx.x;
    if (e < EE) atomicAdd(&cnt[dst[e] * NREL + et[e]], 1);
}

__global__ __launch_bounds__(256) void scanA_k(const int* __restrict__ cnt,
                                               int* __restrict__ off,
                                               int* __restrict__ bsum, int n) {
    __shared__ int sh[256];
    int t = threadIdx.x;
    int base = blockIdx.x * 512 + t * 2;
    int v0 = (base < n) ? cnt[base] : 0;
    int v1 = (base + 1 < n) ? cnt[base + 1] : 0;
    int s = v0 + v1;
    sh[t] = s; __syncthreads();
    for (int o = 1; o < 256; o <<= 1) {
        int u = (t >= o) ? sh[t - o] : 0;
        __syncthreads();
        sh[t] += u;
        __syncthreads();
    }
    int excl = sh[t] - s;
    if (base < n)     off[base]     = excl;
    if (base + 1 < n) off[base + 1] = excl + v0;
    if (t == 255) bsum[blockIdx.x] = sh[255];
}

__global__ __launch_bounds__(1024) void scanB_k(int* __restrict__ bsum, int nb) {
    __shared__ int sh[1024];
    int t = threadIdx.x;
    int s = (t < nb) ? bsum[t] : 0;
    sh[t] = s; __syncthreads();
    for (int o = 1; o < 1024; o <<= 1) {
        int u = (t >= o) ? sh[t - o] : 0;
        __syncthreads();
        sh[t] += u;
        __syncthreads();
    }
    if (t < nb) bsum[t] = sh[t] - s;
}

__global__ __launch_bounds__(256) void scanC_k(int* __restrict__ off,
                                               const int* __restrict__ bsum, int n) {
    int i = blockIdx.x * 256 + threadIdx.x;
    if (i < n) off[i] += bsum[i >> 9];
    if (i == 0) off[n] = EE;
}

__global__ __launch_bounds__(256) void copyint_k(const int* __restrict__ a,
                                                 int* __restrict__ b, int n) {
    int i = blockIdx.x * 256 + threadIdx.x;
    if (i < n) b[i] = a[i];
}

__global__ __launch_bounds__(256) void fill_k(const int* __restrict__ src,
                                              const int* __restrict__ dst,
                                              const int* __restrict__ et,
                                              int* __restrict__ cur,
                                              int* __restrict__ es) {
    int e = blockIdx.x * 256 + threadIdx.x;
    if (e < EE) {
        int key = dst[e] * NREL + et[e];
        int p = atomicAdd(&cur[key], 1);
        es[p] = src[e];
    }
}

// per-CSR-position packed src|rel and mean-weight: ep[p] = src | rel<<24,
// wgt[p] = 1/cnt(cell).  Lets the gather loop run FLAT over all 6 relations
// of a node (avg 16 edges) with real unroll ILP, instead of 6 serial cells
// of avg 2.7 edges (R10 diagnosis: gagg latency-bound at 22% HBM).
__global__ __launch_bounds__(256) void wgt_k(const int* __restrict__ off,
                                             const int* __restrict__ es,
                                             int* __restrict__ ep,
                                             float* __restrict__ wgt) {
    int c = blockIdx.x * 256 + threadIdx.x;
    if (c >= NCELL) return;
    int beg = off[c], end = off[c + 1];
    if (end <= beg) return;
    float inv = 1.f / (float)(end - beg);
    int rtag = (c % NREL) << 24;
    for (int p = beg; p < end; ++p) {
        ep[p] = es[p] | rtag;
        wgt[p] = inv;
    }
}

// ---------------- casts ----------------
__global__ __launch_bounds__(256) void cast_x_k(const float* __restrict__ x,
                                                short* __restrict__ xb, int n4) {
    int i = blockIdx.x * 256 + threadIdx.x;
    if (i < n4) {
        float4 v = ((const float4*)x)[i];
        s16x4 o;
        o[0] = f2b(v.x); o[1] = f2b(v.y); o[2] = f2b(v.z); o[3] = f2b(v.w);
        ((s16x4*)xb)[i] = o;
    }
}

// BT[Ncols][K] = [root | W_0 .. W_5]^T (bf16).  root: [K][D], W: [NREL][K][D].
// Encoder matrices: W==null, Ncols==D.
__global__ __launch_bounds__(256) void wtcat2_k(const float* __restrict__ root,
                                                const float* __restrict__ W,
                                                int K, int D, int Ncols,
                                                short* __restrict__ BT) {
    int i = blockIdx.x * 256 + threadIdx.x;
    if (i >= Ncols * K) return;
    int n = i / K, k = i - n * K;
    float v;
    if (n < D) {
        v = root[(size_t)k * D + n];
    } else {
        int nn = n - D;
        int r = nn / D, c = nn - r * D;
        v = W[((size_t)r * K + k) * D + c];
    }
    BT[(size_t)n * K + k] = f2b(v);
}

// ---------------- dual-problem bf16 MFMA GEMM (R6-proven, plain stores) ----
#define ACH(R, q) ((((R) << 2) | ((q) ^ ((R) & 3) ^ (((R) >> 2) & 1))) * 8)

__global__ __launch_bounds__(256) void gemm2_k(
    const short* __restrict__ A1, const short* __restrict__ B1,
    const float* __restrict__ bias1, int relu1,
    short* __restrict__ Cb1, int ldcb1, float* __restrict__ Cf1, int ldcf1,
    const short* __restrict__ A2, const short* __restrict__ B2,
    const float* __restrict__ bias2, int relu2,
    short* __restrict__ Cb2, int ldcb2, float* __restrict__ Cf2, int ldcf2,
    int M, int K, int nby1) {
    __shared__ __align__(16) char smem[16384];
    short* As = (short*)smem;                // [128*32] bf16
    short* Bs = As + 128 * 32;               // [128*32] bf16
    const int tid = threadIdx.x;
    const int wave = tid >> 6, lane = tid & 63;
    const int wm = (wave & 1) * 64, wn = (wave >> 1) * 64;
    const int l16 = lane & 15, quad = lane >> 4;
    const int bm = blockIdx.x * 128;

    const short* A; const short* BT; const float* bias;
    int relu; short* Cb; int ldcb; float* Cf; int ldcf; int bn;
    if ((int)blockIdx.y < nby1) {
        A = A1; BT = B1; bias = bias1; relu = relu1;
        Cb = Cb1; ldcb = ldcb1; Cf = Cf1; ldcf = ldcf1;
        bn = blockIdx.y * 128;
    } else {
        A = A2; BT = B2; bias = bias2; relu = relu2;
        Cb = Cb2; ldcb = ldcb2; Cf = Cf2; ldcf = ldcf2;
        bn = (blockIdx.y - nby1) * 128;
    }

    // staging slots (linear DMA dest == tid order), pre-swizzled source coords
    const int s0 = tid, s1 = tid + 256;
    const int r0 = s0 >> 2, c0 = (s0 & 3) ^ (r0 & 3) ^ ((r0 >> 2) & 1);
    const int r1 = s1 >> 2, c1 = (s1 & 3) ^ (r1 & 3) ^ ((r1 >> 2) & 1);

    f32x4 acc[4][4];
    #pragma unroll
    for (int i = 0; i < 4; ++i)
        #pragma unroll
        for (int j = 0; j < 4; ++j)
            acc[i][j] = (f32x4)0.f;

    for (int k0 = 0; k0 < K; k0 += 32) {
        gload16(A + (size_t)(bm + r0) * K + k0 + c0 * 8, As + s0 * 8);
        gload16(A + (size_t)(bm + r1) * K + k0 + c1 * 8, As + s1 * 8);
        gload16(BT + (size_t)(bn + r0) * K + k0 + c0 * 8, Bs + s0 * 8);
        gload16(BT + (size_t)(bn + r1) * K + k0 + c1 * 8, Bs + s1 * 8);
        __syncthreads();
        bf16x8 af[4], bf[4];
        #pragma unroll
        for (int mt = 0; mt < 4; ++mt)
            af[mt] = *(const bf16x8*)&As[ACH(wm + mt * 16 + l16, quad)];
        #pragma unroll
        for (int nt = 0; nt < 4; ++nt)
            bf[nt] = *(const bf16x8*)&Bs[ACH(wn + nt * 16 + l16, quad)];
        #pragma unroll
        for (int mt = 0; mt < 4; ++mt)
            #pragma unroll
            for (int nt = 0; nt < 4; ++nt)
                acc[mt][nt] = __builtin_amdgcn_mfma_f32_16x16x32_bf16(
                    af[mt], bf[nt], acc[mt][nt], 0, 0, 0);
        __syncthreads();
    }

    float bv[4];
    #pragma unroll
    for (int nt = 0; nt < 4; ++nt)
        bv[nt] = bias ? bias[bn + wn + nt * 16 + l16] : 0.f;

    // slab row: sr = (wave&1)*16 + quad*4 + r  <->  grow = bm + (sr>>4)*64 + mt*16 + (sr&15)
    if (Cb) {
        short* Es = (short*)smem;            // [32][128] bf16 slab
        #pragma unroll
        for (int mt = 0; mt < 4; ++mt) {
            __syncthreads();
            int srb = (wave & 1) * 16 + quad * 4;
            #pragma unroll
            for (int nt = 0; nt < 4; ++nt) {
                int sc = wn + nt * 16 + l16;
                #pragma unroll
                for (int r = 0; r < 4; ++r) {
                    float v = acc[mt][nt][r] + bv[nt];
                    if (relu) v = fmaxf(v, 0.f);
                    Es[(srb + r) * 128 + sc] = f2b(v);
                }
            }
            __syncthreads();
            #pragma unroll
            for (int h = 0; h < 2; ++h) {
                int c = tid + h * 256;       // chunk 0..511: 32 rows x 16 chunks
                int rr = c >> 4, cc = c & 15;
                int grow = bm + (rr >> 4) * 64 + mt * 16 + (rr & 15);
                if (grow < M)
                    *(bf16x8*)(Cb + (size_t)grow * ldcb + bn + cc * 8) =
                        *(const bf16x8*)&Es[rr * 128 + cc * 8];
            }
        }
    } else {
        float* Ef = (float*)smem;            // [32][128] f32 slab (16 KB)
        #pragma unroll
        for (int mt = 0; mt < 4; ++mt) {
            __syncthreads();
            int srb = (wave & 1) * 16 + quad * 4;
            #pragma unroll
            for (int nt = 0; nt < 4; ++nt) {
                int sc = wn + nt * 16 + l16;
                #pragma unroll
                for (int r = 0; r < 4; ++r) {
                    float v = acc[mt][nt][r] + bv[nt];
                    if (relu) v = fmaxf(v, 0.f);
                    Ef[(srb + r) * 128 + sc] = v;
                }
            }
            __syncthreads();
            #pragma unroll
            for (int h = 0; h < 4; ++h) {
                int c = tid + h * 256;       // chunk 0..1023: 32 rows x 32 chunks
                int rr = c >> 5, cc = c & 31;
                int grow = bm + (rr >> 4) * 64 + mt * 16 + (rr & 15);
                if (grow < M)
                    *(float4*)(Cf + (size_t)grow * ldcf + bn + cc * 4) =
                        *(const float4*)&Ef[rr * 128 + cc * 4];
            }
        }
    }
}

// ---------------- flat-edge gather-aggregate (tier-A path) ----------------
// out[i] = H[i, 0:D] + sum_{p in [off[6i], off[6i+6])} wgt[p] *
//          H[src(p), (1+rel(p))*D : +D]   (+bias, +relu)
// One flat loop over ALL of a node's edges (avg 16), 4-deep unrolled:
// 4 independent (ep,wgt) stream loads + 4 independent 512B H-gathers in
// flight, vs R10's 6 serial cells of avg 2.7 edges with ~1 load in flight.
template<int D>
__global__ __launch_bounds__(256) void gagg2_k(
    const short* __restrict__ H, int ldh,
    const int* __restrict__ off,
    const int* __restrict__ ep, const float* __restrict__ wgt,
    const float* __restrict__ bias, int relu,
    short* __restrict__ Ob, float* __restrict__ Of, int ldo) {
    constexpr int LPN = D / 4;          // lanes per node (64 or 32)
    constexpr int NPB = 256 / LPN;      // nodes per block (4 or 8)
    int sub = threadIdx.x / LPN, lane = threadIdx.x % LPN;
    int node = blockIdx.x * NPB + sub;
    if (node >= NN) return;
    int c0 = lane * 4;
    const short* Hc = H + c0 + D;       // relation blocks start at D

    s16x4 sv = *(const s16x4*)(H + (size_t)node * ldh + c0);
    float a0 = b2f(sv[0]), a1 = b2f(sv[1]), a2 = b2f(sv[2]), a3 = b2f(sv[3]);

    int jb = off[node * NREL], je = off[node * NREL + NREL];
    int j = jb;
    for (; j + 3 < je; j += 4) {
        int u0 = ep[j], u1 = ep[j + 1], u2 = ep[j + 2], u3 = ep[j + 3];
        float w0 = wgt[j], w1 = wgt[j + 1], w2 = wgt[j + 2], w3 = wgt[j + 3];
        s16x4 x0 = *(const s16x4*)(Hc + (size_t)(u0 & 0xFFFFFF) * ldh + (u0 >> 24) * D);
        s16x4 x1 = *(const s16x4*)(Hc + (size_t)(u1 & 0xFFFFFF) * ldh + (u1 >> 24) * D);
        s16x4 x2 = *(const s16x4*)(Hc + (size_t)(u2 & 0xFFFFFF) * ldh + (u2 >> 24) * D);
        s16x4 x3 = *(const s16x4*)(Hc + (size_t)(u3 & 0xFFFFFF) * ldh + (u3 >> 24) * D);
        a0 += w0 * b2f(x0[0]) + w1 * b2f(x1[0]) + w2 * b2f(x2[0]) + w3 * b2f(x3[0]);
        a1 += w0 * b2f(x0[1]) + w1 * b2f(x1[1]) + w2 * b2f(x2[1]) + w3 * b2f(x3[1]);
        a2 += w0 * b2f(x0[2]) + w1 * b2f(x1[2]) + w2 * b2f(x2[2]) + w3 * b2f(x3[2]);
        a3 += w0 * b2f(x0[3]) + w1 * b2f(x1[3]) + w2 * b2f(x2[3]) + w3 * b2f(x3[3]);
    }
    for (; j < je; ++j) {
        int u = ep[j]; float w = wgt[j];
        s16x4 x = *(const s16x4*)(Hc + (size_t)(u & 0xFFFFFF) * ldh + (u >> 24) * D);
        a0 += w * b2f(x[0]); a1 += w * b2f(x[1]);
        a2 += w * b2f(x[2]); a3 += w * b2f(x[3]);
    }
    if (bias) {
        float4 bv = *(const float4*)(bias + c0);
        a0 += bv.x; a1 += bv.y; a2 += bv.z; a3 += bv.w;
    }
    if (relu) {
        a0 = fmaxf(a0, 0.f); a1 = fmaxf(a1, 0.f);
        a2 = fmaxf(a2, 0.f); a3 = fmaxf(a3, 0.f);
    }
    if (Ob) {
        s16x4 o;
        o[0] = f2b(a0); o[1] = f2b(a1); o[2] = f2b(a2); o[3] = f2b(a3);
        *(s16x4*)(Ob + (size_t)node * ldo + c0) = o;
    } else {
        float4 o; o.x = a0; o.y = a1; o.z = a2; o.w = a3;
        *(float4*)(Of + (size_t)node * ldo + c0) = o;
    }
}

// ---------------- per-cell gather-aggregate (fallback tiers) ----------------
template<int D>
__global__ __launch_bounds__(256) void gagg_k(
    const short* __restrict__ H, int ldh,
    int rfirst, int rlast, int colbase, int self0,
    const int* __restrict__ off, const int* __restrict__ es,
    const float* __restrict__ accin,
    const float* __restrict__ bias, int relu,
    short* __restrict__ Ob, float* __restrict__ Of, int ldo) {
    constexpr int LPN = D / 4;
    constexpr int NPB = 256 / LPN;
    int sub = threadIdx.x / LPN, lane = threadIdx.x % LPN;
    int node = blockIdx.x * NPB + sub;
    if (node >= NN) return;
    int c0 = lane * 4;

    float a0, a1, a2, a3;
    if (accin) {
        float4 t = *(const float4*)(accin + (size_t)node * D + c0);
        a0 = t.x; a1 = t.y; a2 = t.z; a3 = t.w;
    } else {
        a0 = a1 = a2 = a3 = 0.f;
    }
    if (self0) {
        s16x4 v = *(const s16x4*)(H + (size_t)node * ldh + c0);
        a0 += b2f(v[0]); a1 += b2f(v[1]); a2 += b2f(v[2]); a3 += b2f(v[3]);
    }
    int cell0 = node * NREL;
    for (int r = rfirst; r < rlast; ++r) {
        int beg = off[cell0 + r], end = off[cell0 + r + 1];
        if (end == beg) continue;
        int colo = (colbase + r) * D + c0;
        float s0 = 0.f, s1 = 0.f, s2 = 0.f, s3 = 0.f;
        int j = beg;
        for (; j + 1 < end; j += 2) {
            s16x4 v = *(const s16x4*)(H + (size_t)es[j] * ldh + colo);
            s16x4 w = *(const s16x4*)(H + (size_t)es[j + 1] * ldh + colo);
            s0 += b2f(v[0]) + b2f(w[0]);
            s1 += b2f(v[1]) + b2f(w[1]);
            s2 += b2f(v[2]) + b2f(w[2]);
            s3 += b2f(v[3]) + b2f(w[3]);
        }
        if (j < end) {
            s16x4 v = *(const s16x4*)(H + (size_t)es[j] * ldh + colo);
            s0 += b2f(v[0]); s1 += b2f(v[1]); s2 += b2f(v[2]); s3 += b2f(v[3]);
        }
        float inv = 1.f / (float)(end - beg);
        a0 += s0 * inv; a1 += s1 * inv; a2 += s2 * inv; a3 += s3 * inv;
    }
    if (bias) {
        float4 bv = *(const float4*)(bias + c0);
        a0 += bv.x; a1 += bv.y; a2 += bv.z; a3 += bv.w;
    }
    if (relu) {
        a0 = fmaxf(a0, 0.f); a1 = fmaxf(a1, 0.f);
        a2 = fmaxf(a2, 0.f); a3 = fmaxf(a3, 0.f);
    }
    if (Ob) {
        s16x4 o;
        o[0] = f2b(a0); o[1] = f2b(a1); o[2] = f2b(a2); o[3] = f2b(a3);
        *(s16x4*)(Ob + (size_t)node * ldo + c0) = o;
    } else {
        float4 o; o.x = a0; o.y = a1; o.z = a2; o.w = a3;
        *(float4*)(Of + (size_t)node * ldo + c0) = o;
    }
}

// ---------------- host ----------------
extern "C" void kernel_launch(void* const* d_in, const int* in_sizes, int n_in,
                              void* d_out, int out_size, void* d_ws, size_t ws_size,
                              hipStream_t stream) {
    const float* x      = (const float*)d_in[0];
    const int*   ei     = (const int*)d_in[1];
    const int*   srcv   = ei;
    const int*   dstv   = ei + EE;
    const int*   et     = (const int*)d_in[2];
    const float* enc_w0 = (const float*)d_in[3];
    const float* enc_b0 = (const float*)d_in[4];
    const float* enc_w1 = (const float*)d_in[5];
    const float* enc_b1 = (const float*)d_in[6];
    const float* enc_w2 = (const float*)d_in[7];
    const float* enc_b2 = (const float*)d_in[8];
    const float* W1     = (const float*)d_in[9];
    const float* root1  = (const float*)d_in[10];
    const float* b1     = (const float*)d_in[11];
    const float* W2     = (const float*)d_in[12];
    const float* root2  = (const float*)d_in[13];
    const float* b2     = (const float*)d_in[14];
    const float* W3     = (const float*)d_in[15];
    const float* root3  = (const float*)d_in[16];
    const float* b3     = (const float*)d_in[17];
    float* out = (float*)d_out;

    char* p = (char*)d_ws;
    auto alloc = [&](size_t bytes) -> char* {
        char* r = p; p += (bytes + 255) & ~(size_t)255; return r;
    };
    short* xb  = (short*)alloc((size_t)NPAD * INC * 2);
    short* g1  = (short*)alloc((size_t)NPAD * OUTC * 2);
    short* g2  = (short*)alloc((size_t)NPAD * OUTC * 2);
    short* BT1 = (short*)alloc((size_t)1792 * INC * 2);    // [root1|W1_0..5]^T
    short* BT2 = (short*)alloc((size_t)1792 * OUTC * 2);   // [root2|W2_0..5]^T
    short* BT3 = (short*)alloc((size_t)896 * OUTC * 2);    // [root3|W3_0..5]^T
    short* ET0 = (short*)alloc((size_t)OUTC * INC * 2);
    short* ET1 = (short*)alloc((size_t)OUTC * OUTC * 2);
    short* ET2 = (short*)alloc((size_t)HALF * OUTC * 2);
    int* CNT  = (int*)alloc((size_t)NCELL * 4);
    int* OFF  = (int*)alloc((size_t)(NCELL + 1) * 4);
    int* CUR  = (int*)alloc((size_t)NCELL * 4);
    int* ES   = (int*)alloc((size_t)EE * 4);
    int* EP   = (int*)alloc((size_t)EE * 4);
    float* WG = (float*)alloc((size_t)EE * 4);
    int* BSUM = (int*)alloc(1024 * 4);
    size_t fixed = (size_t)(p - (char*)d_ws);

    const size_t Hfull = (size_t)NPAD * 1792 * 2;
    const size_t Esz   = (size_t)NPAD * OUTC * 2;
    // Tier A: full H + e1/e2 (batched conv+enc GEMMs, flat-edge gagg2).
    // Tier B: full H, sequential encoder.  Tier C: relation-split two-pass.
    bool tierA = fixed + Hfull + 2 * Esz + 1024 <= ws_size;
    bool fullH = tierA || (fixed + Hfull + 1024 <= ws_size);
    short* H = (short*)alloc(fullH ? Hfull : (size_t)NPAD * 1024 * 2);
    short* e1 = nullptr; short* e2 = nullptr; float* ACC = nullptr;
    if (tierA) { e1 = (short*)alloc(Esz); e2 = (short*)alloc(Esz); }
    if (!fullH) ACC = (float*)alloc((size_t)NPAD * OUTC * 4);

    // ---- CSR build (once; edge structure shared by all 3 layers)
    hipMemsetAsync(CNT, 0, (size_t)NCELL * 4, stream);
    count_k<<<EE / 256, 256, 0, stream>>>(dstv, et, CNT);
    int nbA = (NCELL + 511) / 512;
    scanA_k<<<nbA, 256, 0, stream>>>(CNT, OFF, BSUM, NCELL);
    scanB_k<<<1, 1024, 0, stream>>>(BSUM, nbA);
    scanC_k<<<(NCELL + 255) / 256, 256, 0, stream>>>(OFF, BSUM, NCELL);
    copyint_k<<<(NCELL + 255) / 256, 256, 0, stream>>>(OFF, CUR, NCELL);
    fill_k<<<EE / 256, 256, 0, stream>>>(srcv, dstv, et, CUR, ES);
    wgt_k<<<(NCELL + 255) / 256, 256, 0, stream>>>(OFF, ES, EP, WG);

    // ---- weight transposes + input cast
    cast_x_k<<<(NN * INC / 4 + 255) / 256, 256, 0, stream>>>(x, xb, NN * INC / 4);
    auto wt = [&](const float* root, const float* W, int K, int D, int Ncols, short* BT) {
        wtcat2_k<<<(Ncols * K + 255) / 256, 256, 0, stream>>>(root, W, K, D, Ncols, BT);
    };
    wt(root1, W1, INC, OUTC, 1792, BT1);
    wt(root2, W2, OUTC, OUTC, 1792, BT2);
    wt(root3, W3, OUTC, HALF, 896, BT3);
    wt(enc_w0, nullptr, INC, OUTC, OUTC, ET0);
    wt(enc_w1, nullptr, OUTC, OUTC, OUTC, ET1);
    wt(enc_w2, nullptr, OUTC, HALF, HALF, ET2);

    // single-problem GEMM (duplicated descriptor)
    auto gemm1 = [&](const short* A, const short* BT, int M, int K, int Ncols,
                     const float* bias, int relu, short* Cb, int ldcb, float* Cf, int ldcf) {
        dim3 grid((M + 127) / 128, Ncols / 128);
        gemm2_k<<<grid, 256, 0, stream>>>(A, BT, bias, relu, Cb, ldcb, Cf, ldcf,
                                          A, BT, bias, relu, Cb, ldcb, Cf, ldcf,
                                          M, K, grid.y);
    };

    if (tierA) {
        // ---- batch 1: [conv1-H (N=1792) | enc1 (N=256)], K=128, A=xb both
        gemm2_k<<<dim3(391, 16), 256, 0, stream>>>(
            xb, BT1, nullptr, 0, H, 1792, nullptr, 0,
            xb, ET0, enc_b0, 1, e1, OUTC, nullptr, 0,
            NN, INC, 14);
        gagg2_k<256><<<12500, 256, 0, stream>>>(H, 1792, OFF, EP, WG,
            b1, 1, g1, nullptr, OUTC);
        // ---- batch 2: [conv2-H (N=1792, A=g1) | enc2 (N=256, A=e1)], K=256
        gemm2_k<<<dim3(391, 16), 256, 0, stream>>>(
            g1, BT2, nullptr, 0, H, 1792, nullptr, 0,
            e1, ET1, enc_b1, 1, e2, OUTC, nullptr, 0,
            NN, OUTC, 14);
        gagg2_k<256><<<12500, 256, 0, stream>>>(H, 1792, OFF, EP, WG,
            b2, 1, g2, nullptr, OUTC);
        // ---- batch 3: [conv3-H (N=896, A=g2) | enc3 (N=128, A=e2 -> out f32)], K=256
        gemm2_k<<<dim3(391, 8), 256, 0, stream>>>(
            g2, BT3, nullptr, 0, H, 896, nullptr, 0,
            e2, ET2, enc_b2, 0, nullptr, 0, out, OUTC,
            NN, OUTC, 7);
        gagg2_k<128><<<6250, 256, 0, stream>>>(H, 896, OFF, EP, WG,
            b3, 0, nullptr, out + HALF, OUTC);
        return;
    }

    // ---- fallback: sequential encoder, then conv layers
    gemm1(xb, ET0, NN, INC, OUTC, enc_b0, 1, g1, OUTC, nullptr, 0);
    gemm1(g1, ET1, NN, OUTC, OUTC, enc_b1, 1, g2, OUTC, nullptr, 0);
    gemm1(g2, ET2, NN, OUTC, HALF, enc_b2, 0, nullptr, 0, out, OUTC);

    auto conv = [&](const short* A, int K, int D, const short* BT,
                    const float* bias, int relu, short* Ob, float* Of) {
        int NPB = 256 / (D / 4);
        int gg = (NN + NPB - 1) / NPB;
        if (fullH) {
            gemm1(A, BT, NN, K, 7 * D, nullptr, 0, H, 7 * D, nullptr, 0);
            if (D == 256)
                gagg_k<256><<<gg, 256, 0, stream>>>(H, 7 * D, 0, NREL, 1, 1,
                    OFF, ES, nullptr, bias, relu, Ob, Of, OUTC);
            else
                gagg_k<128><<<gg, 256, 0, stream>>>(H, 7 * D, 0, NREL, 1, 1,
                    OFF, ES, nullptr, bias, relu, Ob, Of, OUTC);
        } else {
            gemm1(A, BT, NN, K, 4 * D, nullptr, 0, H, 4 * D, nullptr, 0);
            if (D == 256)
                gagg_k<256><<<gg, 256, 0, stream>>>(H, 4 * D, 0, 3, 1, 1,
                    OFF, ES, nullptr, nullptr, 0, nullptr, ACC, D);
            else
                gagg_k<128><<<gg, 256, 0, stream>>>(H, 4 * D, 0, 3, 1, 1,
                    OFF, ES, nullptr, nullptr, 0, nullptr, ACC, D);
            gemm1(A, BT + (size_t)4 * D * (size_t)K, NN, K, 3 * D, nullptr, 0, H, 3 * D, nullptr, 0);
            if (D == 256)
                gagg_k<256><<<gg, 256, 0, stream>>>(H, 3 * D, 3, NREL, -3, 0,
                    OFF, ES, ACC, bias, relu, Ob, Of, OUTC);
            else
                gagg_k<128><<<gg, 256, 0, stream>>>(H, 3 * D, 3, NREL, -3, 0,
                    OFF, ES, ACC, bias, relu, Ob, Of, OUTC);
        }
    };

    conv(xb, INC,  OUTC, BT1, b1, 1, g1, nullptr);        // conv1: K=128, N=1792
    conv(g1, OUTC, OUTC, BT2, b2, 1, g2, nullptr);        // conv2: K=256, N=1792
    conv(g2, OUTC, HALF, BT3, b3, 0, nullptr, out + HALF);// conv3: K=256, N=896
}